// Round 5
// baseline (780.158 us; speedup 1.0000x reference)
//
#include <hip/hip_runtime.h>
#include <hip/hip_fp16.h>

#define NM 100000
#define NNZE 1600000
#define C 128
#define SCAN_BLK 1024
#define NSCAN ((NM + SCAN_BLK - 1) / SCAN_BLK)   // 98
#define NPASS 4

typedef unsigned long long u64;
typedef __attribute__((ext_vector_type(8))) short bf16x8;
typedef __attribute__((ext_vector_type(4))) float f32x4;

__device__ __forceinline__ float sigmoidf_(float x) {
    return 1.0f / (1.0f + __expf(-x));
}
__device__ __forceinline__ short f2bf(float f) {          // fp32 -> bf16 RNE
    unsigned u = __float_as_uint(f);
    return (short)((u + 0x7FFFu + ((u >> 16) & 1u)) >> 16);
}
__device__ __forceinline__ float bf2f(short s) {
    return __uint_as_float(((unsigned)(unsigned short)s) << 16);
}

// Y(fp16) = X @ W via split-bf16 MFMA (xh*Wh + xh*Wl + xl*Wh, rel err ~2^-16).
// Fused epilogue: cs[c] += sum_rows deg[row] * Y[row][c] computed in fp32 from
// the accumulator registers (exact colsum; xm quantization never touches it).
__global__ __launch_bounds__(256) void gemm_mfma(const float* __restrict__ X,
                                                 const float* __restrict__ W,
                                                 __half* __restrict__ Y,
                                                 const float* __restrict__ deg,
                                                 float* __restrict__ cs) {
    __shared__ short Whi[16384];   // [kt][ct][lane][j]  4*8*64*8, 32 KB
    __shared__ short Wlo[16384];
    __shared__ float csum[128];
    int t = threadIdx.x;
    if (t < 128) csum[t] = 0.0f;
    for (int e = t; e < 16384; e += 256) {
        int k = e >> 7, c = e & 127;
        float w = W[e];
        short hi = f2bf(w);
        short lo = f2bf(w - bf2f(hi));
        int kt = k >> 5, kin = k & 31, ct = c >> 4, cin = c & 15;
        int lane = ((kin >> 3) << 4) | cin;   // B[k][c]: lane=(kin/8)*16+cin, j=kin&7
        int idx = (((kt << 3) | ct) << 9) + (lane << 3) + (kin & 7);
        Whi[idx] = hi;
        Wlo[idx] = lo;
    }
    __syncthreads();
    int lane = t & 63;
    int wv = t >> 6;
    int gw = blockIdx.x * 4 + wv;
    int wstride = gridDim.x * 4;
    int r_lane = lane & 15;                  // A row within tile / D col
    int kg = lane >> 4;                      // k-group 0..3 / D row group
    const int NT = NM / 16;                  // 6250 row-tiles (exact)
    float part[8] = {0.f, 0.f, 0.f, 0.f, 0.f, 0.f, 0.f, 0.f};
    for (int tile = gw; tile < NT; tile += wstride) {
        int row = tile * 16 + r_lane;
        bf16x8 ahi[4], alo[4];
#pragma unroll
        for (int kt = 0; kt < 4; ++kt) {
            const float4* xp = (const float4*)&X[(long)row * C + kt * 32 + kg * 8];
            float4 v0 = xp[0];
            float4 v1 = xp[1];
            float vv[8] = {v0.x, v0.y, v0.z, v0.w, v1.x, v1.y, v1.z, v1.w};
#pragma unroll
            for (int q = 0; q < 8; ++q) {
                short h = f2bf(vv[q]);
                ahi[kt][q] = h;
                alo[kt][q] = f2bf(vv[q] - bf2f(h));
            }
        }
        int rbase = tile * 16 + kg * 4;      // D: row=rbase+r, col=ct*16+r_lane
        float dg[4];
#pragma unroll
        for (int r = 0; r < 4; ++r) dg[r] = deg[rbase + r];
#pragma unroll
        for (int ct = 0; ct < 8; ++ct) {
            f32x4 acc = {0.f, 0.f, 0.f, 0.f};
#pragma unroll
            for (int kt = 0; kt < 4; ++kt) {
                int bidx = (((kt << 3) | ct) << 9) + (lane << 3);
                bf16x8 bhi = *(bf16x8*)&Whi[bidx];
                bf16x8 blo = *(bf16x8*)&Wlo[bidx];
                acc = __builtin_amdgcn_mfma_f32_16x16x32_bf16(ahi[kt], bhi, acc, 0, 0, 0);
                acc = __builtin_amdgcn_mfma_f32_16x16x32_bf16(ahi[kt], blo, acc, 0, 0, 0);
                acc = __builtin_amdgcn_mfma_f32_16x16x32_bf16(alo[kt], bhi, acc, 0, 0, 0);
            }
            int ccol = ct * 16 + r_lane;
#pragma unroll
            for (int r = 0; r < 4; ++r) {
                Y[(long)(rbase + r) * C + ccol] = __float2half(acc[r]);
                part[ct] += dg[r] * acc[r];
            }
        }
    }
    // reduce part over the 4 kg duplicates, then block-level LDS, then global
#pragma unroll
    for (int ct = 0; ct < 8; ++ct) {
        float p = part[ct];
        p += __shfl_xor(p, 16);
        p += __shfl_xor(p, 32);
        if (lane < 16) atomicAdd(&csum[ct * 16 + lane], p);
    }
    __syncthreads();
    if (t < 128) atomicAdd(&cs[t], csum[t]);
}

// ---- CSR build ----

// row histogram + value-weighted column histogram (deg) in one pass
__global__ __launch_bounds__(256) void hist_kernel(const int* __restrict__ rows,
                                                   const int* __restrict__ cols,
                                                   const float* __restrict__ vals,
                                                   int* __restrict__ cnt,
                                                   float* __restrict__ deg) {
    int e = blockIdx.x * 256 + threadIdx.x;
    if (e < NNZE) {
        atomicAdd(&cnt[rows[e]], 1);
        atomicAdd(&deg[cols[e]], vals[e]);
    }
}

__global__ __launch_bounds__(SCAN_BLK) void scan_partial(const int* __restrict__ cnt,
                                                         int* __restrict__ off,
                                                         int* __restrict__ bsum) {
    __shared__ int wtot[16];
    __shared__ int wexcl[16];
    int t = threadIdx.x;
    int lane = t & 63;
    int wid = t >> 6;
    int i = blockIdx.x * SCAN_BLK + t;
    int v = (i < NM) ? cnt[i] : 0;
    int incl = v;
#pragma unroll
    for (int d = 1; d < 64; d <<= 1) {
        int n = __shfl_up(incl, d);
        if (lane >= d) incl += n;
    }
    if (lane == 63) wtot[wid] = incl;
    __syncthreads();
    if (t < 16) {
        int x = wtot[t];
        int inc = x;
#pragma unroll
        for (int d = 1; d < 16; d <<= 1) {
            int n = __shfl_up(inc, d, 16);
            if (t >= d) inc += n;
        }
        wexcl[t] = inc - x;
        if (t == 15) bsum[blockIdx.x] = inc;
    }
    __syncthreads();
    if (i < NM) off[i] = wexcl[wid] + (incl - v);
}

__global__ __launch_bounds__(128) void scan_blocksums(int* __restrict__ bsum,
                                                      int* __restrict__ bbase,
                                                      int* __restrict__ off) {
    __shared__ int wt[2];
    int t = threadIdx.x;
    int lane = t & 63;
    int wid = t >> 6;
    int v = (t < NSCAN) ? bsum[t] : 0;
    int incl = v;
#pragma unroll
    for (int d = 1; d < 64; d <<= 1) {
        int n = __shfl_up(incl, d);
        if (lane >= d) incl += n;
    }
    if (lane == 63) wt[wid] = incl;
    __syncthreads();
    if (wid == 1) incl += wt[0];
    if (t < NSCAN) bbase[t] = incl - v;
    if (t == 127) off[NM] = incl;
}

__global__ __launch_bounds__(SCAN_BLK) void scan_apply(int* __restrict__ off,
                                                       const int* __restrict__ bbase,
                                                       int* __restrict__ cursor) {
    int i = blockIdx.x * SCAN_BLK + threadIdx.x;
    if (i < NM) {
        int o = off[i] + bbase[blockIdx.x];
        off[i] = o;
        cursor[i] = o;
    }
}

__global__ __launch_bounds__(256) void permute_pass(const int* __restrict__ rows,
                                                    const int* __restrict__ cols,
                                                    const float* __restrict__ vals,
                                                    int* __restrict__ cursor,
                                                    u64* __restrict__ srt,
                                                    int rlo, int rhi) {
    int e0 = blockIdx.x * 256 + threadIdx.x;
    int e1 = e0 + NNZE / 2;
    int r0 = rows[e0];
    int r1 = rows[e1];
    if (r0 >= rlo && r0 < rhi) {
        int p = atomicAdd(&cursor[r0], 1);
        srt[p] = (u64)(unsigned)cols[e0] | ((u64)__float_as_uint(vals[e0]) << 32);
    }
    if (r1 >= rlo && r1 < rhi) {
        int p = atomicAdd(&cursor[r1], 1);
        srt[p] = (u64)(unsigned)cols[e1] | ((u64)__float_as_uint(vals[e1]) << 32);
    }
}

// h[m] = sum val_i * xm[col_i] — fp16 gather (256 B/row), fp32 accumulate,
// unroll-8 for memory-level parallelism
__global__ __launch_bounds__(256) void spmm_csr(const int* __restrict__ off,
                                                const u64* __restrict__ srt,
                                                const __half* __restrict__ xmh,
                                                float* __restrict__ h) {
    int wid = threadIdx.x >> 6;
    int lane = threadIdx.x & 63;
    int m = blockIdx.x * 4 + wid;
    int s = off[m], e = off[m + 1];
    int c = lane * 2;
    float2 acc[8];
#pragma unroll
    for (int j = 0; j < 8; ++j) acc[j] = make_float2(0.f, 0.f);
    int i = s;
    for (; i + 7 < e; i += 8) {
        u64 p[8];
#pragma unroll
        for (int j = 0; j < 8; ++j) p[j] = srt[i + j];
        float2 xf[8];
#pragma unroll
        for (int j = 0; j < 8; ++j) {
            int cj = (int)(p[j] & 0xffffffffu);
            __half2 hx = *(const __half2*)&xmh[(long)cj * C + c];
            xf[j] = __half22float2(hx);
        }
#pragma unroll
        for (int j = 0; j < 8; ++j) {
            float v = __uint_as_float((unsigned)(p[j] >> 32));
            acc[j].x += v * xf[j].x;
            acc[j].y += v * xf[j].y;
        }
    }
    for (; i < e; ++i) {
        u64 p0 = srt[i];
        int c0 = (int)(p0 & 0xffffffffu);
        float v0 = __uint_as_float((unsigned)(p0 >> 32));
        __half2 hx = *(const __half2*)&xmh[(long)c0 * C + c];
        float2 xf = __half22float2(hx);
        acc[0].x += v0 * xf.x;
        acc[0].y += v0 * xf.y;
    }
#pragma unroll
    for (int j = 1; j < 8; ++j) {
        acc[0].x += acc[j].x;
        acc[0].y += acc[j].y;
    }
    *(float2*)&h[(long)m * C + c] = acc[0];
}

__global__ __launch_bounds__(256) void final_kernel(float* h1out,
                                                    const float* __restrict__ h2,
                                                    const float* __restrict__ cs1,
                                                    const float* __restrict__ cs2) {
    int wave = threadIdx.x >> 6;
    int lane = threadIdx.x & 63;
    long m = (long)blockIdx.x * 4 + wave;
    int c = lane * 2;
    float2 a = *(const float2*)&h1out[m * C + c];
    float2 b = *(const float2*)&h2[m * C + c];
    float w1a = fmaxf(sigmoidf_(cs1[c]), 0.0f);
    float w1b = fmaxf(sigmoidf_(cs1[c + 1]), 0.0f);
    float w2a = fmaxf(sigmoidf_(cs2[c]), 0.0f);
    float w2b = fmaxf(sigmoidf_(cs2[c + 1]), 0.0f);
    float d1 = w1a * a.x + w1b * a.y;
    float d2 = w2a * b.x + w2b * b.y;
#pragma unroll
    for (int off = 32; off; off >>= 1) {
        d1 += __shfl_xor(d1, off);
        d2 += __shfl_xor(d2, off);
    }
    float s1 = sigmoidf_(d1);
    float s2 = sigmoidf_(d2);
    float2 o;
    o.x = sigmoidf_(0.5f * (s1 * a.x + s2 * b.x));
    o.y = sigmoidf_(0.5f * (s1 * a.y + s2 * b.y));
    *(float2*)&h1out[m * C + c] = o;
}

static void run_conv(const float* x, const float* W,
                     const int* nr, const int* nc, const float* nv,
                     __half* xmh, float* h, float* cs,
                     int* cnt, float* deg, int* off, int* cursor,
                     int* bsum, int* bbase, u64* srt, hipStream_t stream) {
    const int gE = NNZE / 256;                     // 6250

    hipMemsetAsync(cnt, 0, (size_t)2 * NM * sizeof(int), stream);  // cnt + deg
    hist_kernel<<<gE, 256, 0, stream>>>(nr, nc, nv, cnt, deg);
    scan_partial<<<NSCAN, SCAN_BLK, 0, stream>>>(cnt, off, bsum);
    scan_blocksums<<<1, 128, 0, stream>>>(bsum, bbase, off);
    scan_apply<<<NSCAN, SCAN_BLK, 0, stream>>>(off, bbase, cursor);
    for (int p = 0; p < NPASS; ++p) {
        int rlo = p * (NM / NPASS);
        int rhi = (p + 1) * (NM / NPASS);
        permute_pass<<<NNZE / 512, 256, 0, stream>>>(nr, nc, nv, cursor, srt, rlo, rhi);
    }
    gemm_mfma<<<512, 256, 0, stream>>>(x, W, xmh, deg, cs);
    spmm_csr<<<NM / 4, 256, 0, stream>>>(off, srt, xmh, h);
}

extern "C" void kernel_launch(void* const* d_in, const int* in_sizes, int n_in,
                              void* d_out, int out_size, void* d_ws, size_t ws_size,
                              hipStream_t stream) {
    const float* x1 = (const float*)d_in[0];
    const float* x2 = (const float*)d_in[1];
    const int*   n1r = (const int*)d_in[2];
    const int*   n1c = (const int*)d_in[3];
    const float* n1v = (const float*)d_in[4];
    const int*   n2r = (const int*)d_in[5];
    const int*   n2c = (const int*)d_in[6];
    const float* n2v = (const float*)d_in[7];
    const float* W1 = (const float*)d_in[8];
    const float* W2 = (const float*)d_in[9];

    float* h1 = (float*)d_out;                     // NM*C fp32
    char* ws = (char*)d_ws;
    size_t o = 0;
    __half* xmh = (__half*)(ws + o); o += (size_t)NM * C * sizeof(__half);  // 25.6MB
    float* h2 = (float*)(ws + o);    o += (size_t)NM * C * sizeof(float);   // 51.2MB
    float* cs = (float*)(ws + o);    o += 256 * sizeof(float);
    int* cnt    = (int*)(ws + o);    o += (size_t)NM * sizeof(int);
    float* deg  = (float*)(ws + o);  o += (size_t)NM * sizeof(float);       // contiguous w/ cnt
    int* off    = (int*)(ws + o);    o += (size_t)(NM + 1) * sizeof(int);
    int* cursor = (int*)(ws + o);    o += (size_t)NM * sizeof(int);
    int* bsum   = (int*)(ws + o);    o += (size_t)NSCAN * sizeof(int);
    int* bbase  = (int*)(ws + o);    o += (size_t)NSCAN * sizeof(int);
    o = (o + 7) & ~(size_t)7;
    u64* srt    = (u64*)(ws + o);    o += (size_t)NNZE * sizeof(u64);       // 12.8MB

    hipMemsetAsync(cs, 0, 256 * sizeof(float), stream);

    run_conv(x1, W1, n1r, n1c, n1v, xmh, h1, cs,
             cnt, deg, off, cursor, bsum, bbase, srt, stream);
    run_conv(x2, W2, n2r, n2c, n2v, xmh, h2, cs + 128,
             cnt, deg, off, cursor, bsum, bbase, srt, stream);

    final_kernel<<<NM / 4, 256, 0, stream>>>(h1, h2, cs, cs + 128);
}

// Round 6
// 547.631 us; speedup vs baseline: 1.4246x; 1.4246x over previous
//
#include <hip/hip_runtime.h>
#include <hip/hip_fp16.h>

#define NM 100000
#define NNZE 1600000
#define C 128
#define NBKT ((NM + 255) / 256)          // 391 coarse buckets (256 rows each)
#define NPB  ((NNZE + 4095) / 4096)      // 391 blocks of 4096 entries

typedef unsigned long long u64;
typedef __attribute__((ext_vector_type(8))) short bf16x8;
typedef __attribute__((ext_vector_type(4))) float f32x4;

__device__ __forceinline__ float sigmoidf_(float x) {
    return 1.0f / (1.0f + __expf(-x));
}
__device__ __forceinline__ short f2bf(float f) {          // fp32 -> bf16 RNE
    unsigned u = __float_as_uint(f);
    return (short)((u + 0x7FFFu + ((u >> 16) & 1u)) >> 16);
}
__device__ __forceinline__ float bf2f(short s) {
    return __uint_as_float(((unsigned)(unsigned short)s) << 16);
}

// Y(fp16) = X @ W via split-bf16 MFMA (xh*Wh + xh*Wl + xl*Wh, rel err ~2^-16).
// Fused epilogue: cs[c] += sum_rows deg[row]*acc (exact fp32 colsum).
__global__ __launch_bounds__(256) void gemm_mfma(const float* __restrict__ X,
                                                 const float* __restrict__ W,
                                                 __half* __restrict__ Y,
                                                 const float* __restrict__ deg,
                                                 float* __restrict__ cs) {
    __shared__ short Whi[16384];   // [kt][ct][lane][j]  4*8*64*8, 32 KB
    __shared__ short Wlo[16384];
    __shared__ float csum[128];
    int t = threadIdx.x;
    if (t < 128) csum[t] = 0.0f;
    for (int e = t; e < 16384; e += 256) {
        int k = e >> 7, c = e & 127;
        float w = W[e];
        short hi = f2bf(w);
        short lo = f2bf(w - bf2f(hi));
        int kt = k >> 5, kin = k & 31, ct = c >> 4, cin = c & 15;
        int lane = ((kin >> 3) << 4) | cin;
        int idx = (((kt << 3) | ct) << 9) + (lane << 3) + (kin & 7);
        Whi[idx] = hi;
        Wlo[idx] = lo;
    }
    __syncthreads();
    int lane = t & 63;
    int wv = t >> 6;
    int gw = blockIdx.x * 4 + wv;
    int wstride = gridDim.x * 4;
    int r_lane = lane & 15;
    int kg = lane >> 4;
    const int NT = NM / 16;
    float part[8] = {0.f, 0.f, 0.f, 0.f, 0.f, 0.f, 0.f, 0.f};
    for (int tile = gw; tile < NT; tile += wstride) {
        int row = tile * 16 + r_lane;
        bf16x8 ahi[4], alo[4];
#pragma unroll
        for (int kt = 0; kt < 4; ++kt) {
            const float4* xp = (const float4*)&X[(long)row * C + kt * 32 + kg * 8];
            float4 v0 = xp[0];
            float4 v1 = xp[1];
            float vv[8] = {v0.x, v0.y, v0.z, v0.w, v1.x, v1.y, v1.z, v1.w};
#pragma unroll
            for (int q = 0; q < 8; ++q) {
                short h = f2bf(vv[q]);
                ahi[kt][q] = h;
                alo[kt][q] = f2bf(vv[q] - bf2f(h));
            }
        }
        int rbase = tile * 16 + kg * 4;
        float dg[4];
#pragma unroll
        for (int r = 0; r < 4; ++r) dg[r] = deg[rbase + r];
#pragma unroll
        for (int ct = 0; ct < 8; ++ct) {
            f32x4 acc = {0.f, 0.f, 0.f, 0.f};
#pragma unroll
            for (int kt = 0; kt < 4; ++kt) {
                int bidx = (((kt << 3) | ct) << 9) + (lane << 3);
                bf16x8 bhi = *(bf16x8*)&Whi[bidx];
                bf16x8 blo = *(bf16x8*)&Wlo[bidx];
                acc = __builtin_amdgcn_mfma_f32_16x16x32_bf16(ahi[kt], bhi, acc, 0, 0, 0);
                acc = __builtin_amdgcn_mfma_f32_16x16x32_bf16(ahi[kt], blo, acc, 0, 0, 0);
                acc = __builtin_amdgcn_mfma_f32_16x16x32_bf16(alo[kt], bhi, acc, 0, 0, 0);
            }
            int ccol = ct * 16 + r_lane;
#pragma unroll
            for (int r = 0; r < 4; ++r) {
                Y[(long)(rbase + r) * C + ccol] = __float2half(acc[r]);
                part[ct] += dg[r] * acc[r];
            }
        }
    }
#pragma unroll
    for (int ct = 0; ct < 8; ++ct) {
        float p = part[ct];
        p += __shfl_xor(p, 16);
        p += __shfl_xor(p, 32);
        if (lane < 16) atomicAdd(&csum[ct * 16 + lane], p);
    }
    __syncthreads();
    if (t < 128) atomicAdd(&cs[t], csum[t]);
}

// ---- bucket-sort CSR build (LDS-aggregated; global atomics: 1.6M deg + 2*153K) ----

// deg[col] += val (global atomics) + coarse row-bucket histogram (LDS, flushed once)
__global__ __launch_bounds__(256) void hist2_kernel(const int* __restrict__ rows,
                                                    const int* __restrict__ cols,
                                                    const float* __restrict__ vals,
                                                    float* __restrict__ deg,
                                                    int* __restrict__ gBktCnt) {
    __shared__ int lcnt[NBKT];
    int t = threadIdx.x;
    for (int j = t; j < NBKT; j += 256) lcnt[j] = 0;
    __syncthreads();
    long base = (long)blockIdx.x * 4096;
#pragma unroll
    for (int i = 0; i < 16; ++i) {
        long e = base + i * 256 + t;
        if (e < NNZE) {
            atomicAdd(&deg[cols[e]], vals[e]);
            atomicAdd(&lcnt[rows[e] >> 8], 1);
        }
    }
    __syncthreads();
    for (int j = t; j < NBKT; j += 256)
        if (lcnt[j]) atomicAdd(&gBktCnt[j], lcnt[j]);
}

// exclusive scan of 391 bucket counts -> bktBase, gCursor; also off[NM], bktBase[NBKT]
__global__ __launch_bounds__(512) void scan_bkt(const int* __restrict__ gBktCnt,
                                                int* __restrict__ bktBase,
                                                int* __restrict__ gCursor,
                                                int* __restrict__ off) {
    __shared__ int wt[8];
    __shared__ int wb[8];
    int t = threadIdx.x;
    int lane = t & 63;
    int wid = t >> 6;
    int v = (t < NBKT) ? gBktCnt[t] : 0;
    int incl = v;
#pragma unroll
    for (int d = 1; d < 64; d <<= 1) {
        int n = __shfl_up(incl, d);
        if (lane >= d) incl += n;
    }
    if (lane == 63) wt[wid] = incl;
    __syncthreads();
    if (t == 0) {
        int r = 0;
#pragma unroll
        for (int i = 0; i < 8; ++i) { wb[i] = r; r += wt[i]; }
    }
    __syncthreads();
    int excl = wb[wid] + incl - v;
    if (t < NBKT) {
        bktBase[t] = excl;
        gCursor[t] = excl;
    }
    if (t == 0) {
        bktBase[NBKT] = NNZE;
        off[NM] = NNZE;
    }
}

// scatter entries into coarse buckets; per-(block,bucket) run reserved with ONE
// global atomic; positions within the run via LDS atomics
__global__ __launch_bounds__(256) void place_kernel(const int* __restrict__ rows,
                                                    const int* __restrict__ cols,
                                                    const float* __restrict__ vals,
                                                    int* __restrict__ gCursor,
                                                    u64* __restrict__ bkt) {
    __shared__ int lcnt[NBKT];
    __shared__ int lbase[NBKT];
    int t = threadIdx.x;
    for (int j = t; j < NBKT; j += 256) lcnt[j] = 0;
    __syncthreads();
    long base = (long)blockIdx.x * 4096;
    int myrow[16];
#pragma unroll
    for (int i = 0; i < 16; ++i) {
        long e = base + i * 256 + t;
        myrow[i] = (e < NNZE) ? rows[e] : -1;
        if (myrow[i] >= 0) atomicAdd(&lcnt[myrow[i] >> 8], 1);
    }
    __syncthreads();
    for (int j = t; j < NBKT; j += 256) {
        int c = lcnt[j];
        lbase[j] = c ? atomicAdd(&gCursor[j], c) : 0;
    }
    __syncthreads();
    for (int j = t; j < NBKT; j += 256) lcnt[j] = 0;
    __syncthreads();
#pragma unroll
    for (int i = 0; i < 16; ++i) {
        long e = base + i * 256 + t;
        if (myrow[i] >= 0) {
            int b = myrow[i] >> 8;
            int p = lbase[b] + atomicAdd(&lcnt[b], 1);
            unsigned meta = ((unsigned)(myrow[i] & 255) << 17) | (unsigned)cols[e];
            bkt[p] = (u64)meta | ((u64)__float_as_uint(vals[e]) << 32);
        }
    }
}

// one block per bucket: LDS row-count + block scan -> off[] (plain stores),
// then scatter (col,val) into final CSR order. Zero global atomics.
__global__ __launch_bounds__(256) void fine_kernel(const int* __restrict__ bktBase,
                                                   const u64* __restrict__ bkt,
                                                   u64* __restrict__ srt,
                                                   int* __restrict__ off) {
    __shared__ int cnt[256];
    __shared__ int excl[256];
    __shared__ int wt[4];
    __shared__ int wb[4];
    int b = blockIdx.x;
    int t = threadIdx.x;
    int base = bktBase[b];
    int n = bktBase[b + 1] - base;
    cnt[t] = 0;
    __syncthreads();
    for (int i = t; i < n; i += 256) {
        unsigned meta = (unsigned)(bkt[base + i] & 0xffffffffu);
        atomicAdd(&cnt[meta >> 17], 1);
    }
    __syncthreads();
    int lane = t & 63;
    int wid = t >> 6;
    int v = cnt[t];
    int incl = v;
#pragma unroll
    for (int d = 1; d < 64; d <<= 1) {
        int nn = __shfl_up(incl, d);
        if (lane >= d) incl += nn;
    }
    if (lane == 63) wt[wid] = incl;
    __syncthreads();
    if (t == 0) {
        int r = 0;
#pragma unroll
        for (int i = 0; i < 4; ++i) { wb[i] = r; r += wt[i]; }
    }
    __syncthreads();
    int ex = wb[wid] + incl - v;
    excl[t] = ex;
    int row = b * 256 + t;
    if (row < NM) off[row] = base + ex;
    cnt[t] = 0;              // reuse as cursor
    __syncthreads();
    for (int i = t; i < n; i += 256) {
        u64 rec = bkt[base + i];
        unsigned meta = (unsigned)(rec & 0xffffffffu);
        int lr = (int)(meta >> 17);
        unsigned col = meta & 0x1ffffu;
        int p = excl[lr] + atomicAdd(&cnt[lr], 1);
        srt[base + p] = (u64)col | (rec & 0xffffffff00000000ull);
    }
}

// h[m] = sum val_i * xm[col_i] — fp16 gather, fp32 accumulate, unroll-8
__global__ __launch_bounds__(256) void spmm_csr(const int* __restrict__ off,
                                                const u64* __restrict__ srt,
                                                const __half* __restrict__ xmh,
                                                float* __restrict__ h) {
    int wid = threadIdx.x >> 6;
    int lane = threadIdx.x & 63;
    int m = blockIdx.x * 4 + wid;
    int s = off[m], e = off[m + 1];
    int c = lane * 2;
    float2 acc[8];
#pragma unroll
    for (int j = 0; j < 8; ++j) acc[j] = make_float2(0.f, 0.f);
    int i = s;
    for (; i + 7 < e; i += 8) {
        u64 p[8];
#pragma unroll
        for (int j = 0; j < 8; ++j) p[j] = srt[i + j];
        float2 xf[8];
#pragma unroll
        for (int j = 0; j < 8; ++j) {
            int cj = (int)(p[j] & 0xffffffffu);
            __half2 hx = *(const __half2*)&xmh[(long)cj * C + c];
            xf[j] = __half22float2(hx);
        }
#pragma unroll
        for (int j = 0; j < 8; ++j) {
            float v = __uint_as_float((unsigned)(p[j] >> 32));
            acc[j].x += v * xf[j].x;
            acc[j].y += v * xf[j].y;
        }
    }
    for (; i < e; ++i) {
        u64 p0 = srt[i];
        int c0 = (int)(p0 & 0xffffffffu);
        float v0 = __uint_as_float((unsigned)(p0 >> 32));
        __half2 hx = *(const __half2*)&xmh[(long)c0 * C + c];
        float2 xf = __half22float2(hx);
        acc[0].x += v0 * xf.x;
        acc[0].y += v0 * xf.y;
    }
#pragma unroll
    for (int j = 1; j < 8; ++j) {
        acc[0].x += acc[j].x;
        acc[0].y += acc[j].y;
    }
    *(float2*)&h[(long)m * C + c] = acc[0];
}

__global__ __launch_bounds__(256) void final_kernel(float* h1out,
                                                    const float* __restrict__ h2,
                                                    const float* __restrict__ cs1,
                                                    const float* __restrict__ cs2) {
    int wave = threadIdx.x >> 6;
    int lane = threadIdx.x & 63;
    long m = (long)blockIdx.x * 4 + wave;
    int c = lane * 2;
    float2 a = *(const float2*)&h1out[m * C + c];
    float2 b = *(const float2*)&h2[m * C + c];
    float w1a = fmaxf(sigmoidf_(cs1[c]), 0.0f);
    float w1b = fmaxf(sigmoidf_(cs1[c + 1]), 0.0f);
    float w2a = fmaxf(sigmoidf_(cs2[c]), 0.0f);
    float w2b = fmaxf(sigmoidf_(cs2[c + 1]), 0.0f);
    float d1 = w1a * a.x + w1b * a.y;
    float d2 = w2a * b.x + w2b * b.y;
#pragma unroll
    for (int off = 32; off; off >>= 1) {
        d1 += __shfl_xor(d1, off);
        d2 += __shfl_xor(d2, off);
    }
    float s1 = sigmoidf_(d1);
    float s2 = sigmoidf_(d2);
    float2 o;
    o.x = sigmoidf_(0.5f * (s1 * a.x + s2 * b.x));
    o.y = sigmoidf_(0.5f * (s1 * a.y + s2 * b.y));
    *(float2*)&h1out[m * C + c] = o;
}

static void run_conv(const float* x, const float* W,
                     const int* nr, const int* nc, const float* nv,
                     __half* xmh, float* h, float* cs,
                     float* deg, int* gBktCnt, int* bktBase, int* gCursor,
                     int* off, u64* bkt, u64* srt, hipStream_t stream) {
    // deg + gBktCnt are contiguous: one memset
    hipMemsetAsync(deg, 0, (size_t)(NM + NBKT) * sizeof(int), stream);
    hist2_kernel<<<NPB, 256, 0, stream>>>(nr, nc, nv, deg, gBktCnt);
    scan_bkt<<<1, 512, 0, stream>>>(gBktCnt, bktBase, gCursor, off);
    place_kernel<<<NPB, 256, 0, stream>>>(nr, nc, nv, gCursor, bkt);
    fine_kernel<<<NBKT, 256, 0, stream>>>(bktBase, bkt, srt, off);
    gemm_mfma<<<512, 256, 0, stream>>>(x, W, xmh, deg, cs);
    spmm_csr<<<NM / 4, 256, 0, stream>>>(off, srt, xmh, h);
}

extern "C" void kernel_launch(void* const* d_in, const int* in_sizes, int n_in,
                              void* d_out, int out_size, void* d_ws, size_t ws_size,
                              hipStream_t stream) {
    const float* x1 = (const float*)d_in[0];
    const float* x2 = (const float*)d_in[1];
    const int*   n1r = (const int*)d_in[2];
    const int*   n1c = (const int*)d_in[3];
    const float* n1v = (const float*)d_in[4];
    const int*   n2r = (const int*)d_in[5];
    const int*   n2c = (const int*)d_in[6];
    const float* n2v = (const float*)d_in[7];
    const float* W1 = (const float*)d_in[8];
    const float* W2 = (const float*)d_in[9];

    float* h1 = (float*)d_out;                     // NM*C fp32
    char* ws = (char*)d_ws;
    size_t o = 0;
    __half* xmh = (__half*)(ws + o); o += (size_t)NM * C * sizeof(__half);  // 25.6MB
    float* h2 = (float*)(ws + o);    o += (size_t)NM * C * sizeof(float);   // 51.2MB
    float* cs = (float*)(ws + o);    o += 256 * sizeof(float);
    float* deg  = (float*)(ws + o);  o += (size_t)NM * sizeof(float);       // 400KB
    int* gBktCnt = (int*)(ws + o);   o += (size_t)NBKT * sizeof(int);       // contiguous w/ deg
    int* bktBase = (int*)(ws + o);   o += (size_t)(NBKT + 1) * sizeof(int);
    int* gCursor = (int*)(ws + o);   o += (size_t)NBKT * sizeof(int);
    int* off    = (int*)(ws + o);    o += (size_t)(NM + 1) * sizeof(int);
    o = (o + 7) & ~(size_t)7;
    u64* bkt    = (u64*)(ws + o);    o += (size_t)NNZE * sizeof(u64);       // 12.8MB
    u64* srt    = (u64*)(ws + o);    o += (size_t)NNZE * sizeof(u64);       // 12.8MB

    hipMemsetAsync(cs, 0, 256 * sizeof(float), stream);

    run_conv(x1, W1, n1r, n1c, n1v, xmh, h1, cs,
             deg, gBktCnt, bktBase, gCursor, off, bkt, srt, stream);
    run_conv(x2, W2, n2r, n2c, n2v, xmh, h2, cs + 128,
             deg, gBktCnt, bktBase, gCursor, off, bkt, srt, stream);

    final_kernel<<<NM / 4, 256, 0, stream>>>(h1, h2, cs, cs + 128);
}